// Round 14
// baseline (446.333 us; speedup 1.0000x reference)
//
#include <hip/hip_runtime.h>
#include <math.h>

#define BB 256
#define TT 512
#define KK 128
#define AIDX(i) ((i) + (((i) >> 5) << 2))

// shared-memory layout (floats) for the fused kernel
#define SM_TT    0          // [128][130] transposed trans = 16640
#define SM_AV    16640      // av[2][144] = 288   (vit)  | ev[2][144] (fwd)
#define SM_TAGS  16928      // tagsf[512]
#define SM_RV    17440      // rv[8]
#define SM_RI    17448      // ri[8]
#define SM_LAST  17456      // last_s
#define SM_WMAX  17460      // wmax[16] (fwd)
#define SM_RS    17476      // rs[8]   (fwd)
#define SM_RSC   17484      // rsc[8]  (fwd)
#define SM_TOTAL 17496      // ~70.0 KB -> 2 blocks/CU

typedef float v2f __attribute__((ext_vector_type(2)));
typedef unsigned short u16v2 __attribute__((ext_vector_type(2)));

template<int CTRL>
__device__ __forceinline__ int dpp_i(int x) {
  return __builtin_amdgcn_update_dpp(x, x, CTRL, 0xF, 0xF, true);
}
template<int CTRL>
__device__ __forceinline__ float dpp_f(float x) {
  return __int_as_float(dpp_i<CTRL>(__float_as_int(x)));
}
__device__ __forceinline__ float swz16_f(float x) {
  return __int_as_float(__builtin_amdgcn_ds_swizzle(__float_as_int(x), 0x401F));
}
// barrier that drains LDS only (not vmcnt) — keeps prefetch loads in flight
#define BARRIER_LGKM() asm volatile("s_waitcnt lgkmcnt(0)\ns_barrier" ::: "memory")

// DPP ladder within a 16-lane group: 0xB1 quad_perm xor1, 0x4E quad_perm xor2,
// 0x141 row_half_mirror (xor4 once quad-uniform), 0x140 row_mirror (xor8 once
// 8-uniform). Same verified sequence as the R7 kernel, one extra level.

// ============================================================================
// FUSED kernel: recursion re-tiled to 32 col-groups x 4 cols, 16 row-groups x
// 8 rows (halves per-thread LDS alpha reads: 2x b128 instead of 4x). Barrier
// structure, m-streaming, chase: verbatim R7 (378us verified).
// ============================================================================
__global__ __launch_bounds__(512, 4) void crf_main(
    const float* __restrict__ logits,     // [B,T,K]
    const int* __restrict__ labels,       // [B,T]
    const int* __restrict__ seq_lens,     // [B]
    const float* __restrict__ trans,      // [K,K]
    float* __restrict__ pred_out,         // [B,T] as float (d_out+1)
    float* __restrict__ negll,            // [B] in ws
    float* __restrict__ mOut)             // [B][T][K] in ws (t>=1 valid)
{
  __shared__ __align__(16) float smem[SM_TOTAL];
  const int tid = threadIdx.x;
  // recursion decomposition: 4 cols x 8 rows per thread
  const int rcg = tid >> 4, rrg = tid & 15;
  const int rj0 = rcg * 4, ri0 = rrg * 8;

  if (blockIdx.x < BB) {
    // ================= VITERBI (scan-free) + in-block chase =================
    const int b = blockIdx.x;
    const int L = seq_lens[b];
    float* tT    = smem + SM_TT;                      // [128][130]
    float (*av)[144] = (float(*)[144])(smem + SM_AV);
    float* tagsf = smem + SM_TAGS;
    float* rv    = smem + SM_RV;
    int*   ri    = (int*)(smem + SM_RI);
    int*   last_s = (int*)(smem + SM_LAST);

    // build transposed trans for the chase (coalesced reads, one-time)
    for (int e = tid; e < KK * KK; e += 512) {
      int i = e >> 7, j = e & 127;
      tT[j * 130 + i] = trans[e];
    }

    // T block 8 rows x 4 cols in registers (32 VGPRs)
    v2f tv[8][2];
#pragma unroll
    for (int rr = 0; rr < 8; ++rr) {
      tv[rr][0] = *(const v2f*)&trans[(ri0 + rr) * KK + rj0];
      tv[rr][1] = *(const v2f*)&trans[(ri0 + rr) * KK + rj0 + 2];
    }

    if (tid < KK) av[0][AIDX(tid)] = logits[(b * TT) * KK + tid];

    float4 emC[4], emN[4];
#pragma unroll
    for (int s = 0; s < 4; ++s) {
      int t2 = 1 + s; if (t2 > L - 1) t2 = (L > 1) ? (L - 1) : 0;
      emC[s] = *(const float4*)&logits[(b * TT + t2) * KK + rj0];
    }
    __syncthreads();

    for (int tc = 1; tc < L; tc += 4) {
#pragma unroll
      for (int s = 0; s < 4; ++s) {
        int t2 = tc + 4 + s; if (t2 > L - 1) t2 = L - 1;
        emN[s] = *(const float4*)&logits[(b * TT + t2) * KK + rj0];
      }
#pragma unroll
      for (int s = 0; s < 4; ++s) {
        const int t = tc + s;
        if (t >= L) break;
        const float4* avr = (const float4*)(av[(t & 1) ^ 1] + AIDX(ri0));
        float4 a0 = avr[0], a1 = avr[1];     // rows ri0..ri0+7
        // per-thread max over 8 rows x 4 cols (exact IEEE adds, running max)
        v2f m0 = (v2f){a0.x, a0.x} + tv[0][0];
        v2f m1 = (v2f){a0.x, a0.x} + tv[0][1];
#define ROWMAX(AV, R)                                                          \
        { v2f x0 = (v2f){AV, AV} + tv[R][0];                                   \
          v2f x1 = (v2f){AV, AV} + tv[R][1];                                   \
          m0 = __builtin_elementwise_max(m0, x0);                              \
          m1 = __builtin_elementwise_max(m1, x1); }
        ROWMAX(a0.y, 1) ROWMAX(a0.z, 2) ROWMAX(a0.w, 3)
        ROWMAX(a1.x, 4) ROWMAX(a1.y, 5) ROWMAX(a1.z, 6) ROWMAX(a1.w, 7)
#undef ROWMAX
        // cross-lane max over 16 row-groups: xor1, xor2, xor4, xor8 (DPP)
        {
          v2f o0, o1;
          o0.x = dpp_f<0xB1>(m0.x); o0.y = dpp_f<0xB1>(m0.y);
          o1.x = dpp_f<0xB1>(m1.x); o1.y = dpp_f<0xB1>(m1.y);
          m0 = __builtin_elementwise_max(m0, o0);
          m1 = __builtin_elementwise_max(m1, o1);
          o0.x = dpp_f<0x4E>(m0.x); o0.y = dpp_f<0x4E>(m0.y);
          o1.x = dpp_f<0x4E>(m1.x); o1.y = dpp_f<0x4E>(m1.y);
          m0 = __builtin_elementwise_max(m0, o0);
          m1 = __builtin_elementwise_max(m1, o1);
          o0.x = dpp_f<0x141>(m0.x); o0.y = dpp_f<0x141>(m0.y);
          o1.x = dpp_f<0x141>(m1.x); o1.y = dpp_f<0x141>(m1.y);
          m0 = __builtin_elementwise_max(m0, o0);
          m1 = __builtin_elementwise_max(m1, o1);
          o0.x = dpp_f<0x140>(m0.x); o0.y = dpp_f<0x140>(m0.y);
          o1.x = dpp_f<0x140>(m1.x); o1.y = dpp_f<0x140>(m1.y);
          m0 = __builtin_elementwise_max(m0, o0);
          m1 = __builtin_elementwise_max(m1, o1);
        }
        float4 em2 = emC[s];
        if (rrg == 0) {
          *(float4*)(av[t & 1] + AIDX(rj0)) =
              make_float4(m0.x + em2.x, m0.y + em2.y,
                          m1.x + em2.z, m1.y + em2.w);
          *(float4*)&mOut[(size_t)(b * TT + t) * KK + rj0] =
              make_float4(m0.x, m0.y, m1.x, m1.y);     // stream m_t
        }
        BARRIER_LGKM();
      }
#pragma unroll
      for (int s = 0; s < 4; ++s) emC[s] = emN[s];
    }

    // final argmax across K → last_s (verbatim)
    const float* avf = av[(L - 1) & 1];
    {
      float v = (tid < KK) ? avf[AIDX(tid)] : -3.4e38f;
      int idx = (tid < KK) ? tid : KK;
#pragma unroll
      for (int mm = 1; mm < 64; mm <<= 1) {
        float ov = __shfl_xor(v, mm);
        int oi = __shfl_xor(idx, mm);
        if (ov > v || (ov == v && oi < idx)) { v = ov; idx = oi; }
      }
      if ((tid & 63) == 0) { rv[tid >> 6] = v; ri[tid >> 6] = idx; }
    }
    __syncthreads();
    if (tid == 0) {
      float bv = rv[0]; int bi = ri[0];
#pragma unroll
      for (int w = 1; w < 8; ++w)
        if (rv[w] > bv || (rv[w] == bv && ri[w] < bi)) { bv = rv[w]; bi = ri[w]; }
      *last_s = bi;
    }
    __syncthreads();
    const int last = *last_s;
    for (int t = tid; t < TT; t += 512) tagsf[t] = (float)last;
    // barrier: tagsf visible + drains every wave's vmcnt (mOut in L2)
    __syncthreads();

    if (tid >= 64) return;        // waves 1-7 retire; wave 0 runs the chase
    const int l = tid;

    if (L >= 2) {
      const float* mb = mOut   + (size_t)(b * TT) * KK + 2 * l;
      const float* gb = logits + (size_t)(b * TT) * KK + 2 * l;
      int tag = last;
      v2f mvC = *(const v2f*)&mb[(size_t)(L - 1) * KK];   // m at current step t

      v2f lg0, lg1, lg2, lg3, lg4, lg5, lg6, lg7;
      v2f mv0, mv1, mv2, mv3, mv4, mv5, mv6, mv7;
#define INITLD(P) { int s_ = L - 2 - (P); int sc_ = s_ < 0 ? 0 : s_;           \
      lg##P = *(const v2f*)&gb[(size_t)sc_ * KK];                              \
      mv##P = *(const v2f*)&mb[(size_t)sc_ * KK]; }
      INITLD(0) INITLD(1) INITLD(2) INITLD(3)
      INITLD(4) INITLD(5) INITLD(6) INITLD(7)
#undef INITLD

      int t = L - 1;

#define STEP_BODY(LG, MV, GUARDED)                                             \
      {                                                                        \
        const int tp = t - 1;                                                  \
        v2f aP;                                                                \
        if (GUARDED) aP = (tp >= 1) ? (MV + LG) : LG;                          \
        else         aP = MV + LG;                                             \
        int lanem = tag >> 1;                                                  \
        int txi = __builtin_amdgcn_readlane(__float_as_int(mvC.x), lanem);     \
        int tyi = __builtin_amdgcn_readlane(__float_as_int(mvC.y), lanem);     \
        float target = __int_as_float((tag & 1) ? tyi : txi);                  \
        v2f col = *(const v2f*)&tT[tag * 130 + 2 * l];                         \
        v2f sv = aP + col;                 /* bit-exact phase-1 adds */        \
        bool h0 = (sv.x == target), h1 = (sv.y == target);                     \
        unsigned long long mask = __ballot(h0 || h1);                          \
        int first = __ffsll(mask) - 1;     /* lowest matching lane */          \
        int cand = h0 ? (2 * l) : (2 * l + 1);                                 \
        tag = __builtin_amdgcn_readlane(cand, first);                          \
        if (l == 0) tagsf[tp] = (float)tag;                                    \
        mvC = MV;                                                              \
      }

      while (t >= 9) {
#define MAIN_PHASE(P)                                                          \
        STEP_BODY(lg##P, mv##P, false)                                         \
        { int sN = t - 9; int sc_ = sN < 0 ? 0 : sN;                           \
          lg##P = *(const v2f*)&gb[(size_t)sc_ * KK];                          \
          mv##P = *(const v2f*)&mb[(size_t)sc_ * KK]; }                        \
        --t;
        MAIN_PHASE(0) MAIN_PHASE(1) MAIN_PHASE(2) MAIN_PHASE(3)
        MAIN_PHASE(4) MAIN_PHASE(5) MAIN_PHASE(6) MAIN_PHASE(7)
#undef MAIN_PHASE
      }
      while (t >= 1) {
        const int tp = t - 1;
        int sc_ = tp < 1 ? 0 : tp;
        v2f lgE = *(const v2f*)&gb[(size_t)tp * KK];
        v2f mvE = *(const v2f*)&mb[(size_t)sc_ * KK];
        STEP_BODY(lgE, mvE, true)
        --t;
      }
#undef STEP_BODY
    }
#pragma unroll
    for (int k = 0; k < 8; ++k)
      pred_out[b * TT + l * 8 + k] = tagsf[l * 8 + k];

  } else {
    // ================= FORWARD (log-norm), same re-tile =====================
    const int b = blockIdx.x - BB;
    const int L = seq_lens[b];
    float (*ev)[144] = (float(*)[144])(smem + SM_AV);
    float* wmax = smem + SM_WMAX;
    float* rs   = smem + SM_RS;
    float* rsc  = smem + SM_RSC;

    v2f tw[8][2];
#pragma unroll
    for (int rr = 0; rr < 8; ++rr) {
      v2f t0 = *(const v2f*)&trans[(ri0 + rr) * KK + rj0];
      v2f t1 = *(const v2f*)&trans[(ri0 + rr) * KK + rj0 + 2];
      tw[rr][0].x = __expf(t0.x); tw[rr][0].y = __expf(t0.y);
      tw[rr][1].x = __expf(t1.x); tw[rr][1].y = __expf(t1.y);
    }
    if (tid < KK) ev[0][AIDX(tid)] = __expf(logits[(b * TT) * KK + tid]);
    if (tid < 16) wmax[tid] = 1.0f;

    float4 emC[4], emN[4];
#pragma unroll
    for (int s = 0; s < 4; ++s) {
      int t2 = 1 + s; if (t2 > L - 1) t2 = (L > 1) ? (L - 1) : 0;
      emC[s] = *(const float4*)&logits[(b * TT + t2) * KK + rj0];
    }
    __syncthreads();

    float Cln = 0.0f;
    for (int tc = 1; tc < L; tc += 4) {
#pragma unroll
      for (int s = 0; s < 4; ++s) {
        int t2 = tc + 4 + s; if (t2 > L - 1) t2 = L - 1;
        emN[s] = *(const float4*)&logits[(b * TT + t2) * KK + rj0];
      }
      // renorm factor (exact pow2), once per 4-step chunk (verbatim)
      float r;
      {
        float4 w0 = *(const float4*)&wmax[0];
        float4 w1 = *(const float4*)&wmax[4];
        float4 w2 = *(const float4*)&wmax[8];
        float4 w3 = *(const float4*)&wmax[12];
        float U = fmaxf(fmaxf(fmaxf(w0.x, w0.y), fmaxf(w0.z, w0.w)),
                        fmaxf(fmaxf(w1.x, w1.y), fmaxf(w1.z, w1.w)));
        U = fmaxf(U, fmaxf(fmaxf(fmaxf(w2.x, w2.y), fmaxf(w2.z, w2.w)),
                           fmaxf(fmaxf(w3.x, w3.y), fmaxf(w3.z, w3.w))));
        int ex = (__float_as_int(U) >> 23) & 255;
        r = __int_as_float((254 - ex) << 23);
        Cln += (float)(ex - 127) * 0.6931471805599453f;
      }
#pragma unroll
      for (int s = 0; s < 4; ++s) {
        const int t = tc + s;
        if (t >= L) break;
        const float4* evr = (const float4*)(ev[(t & 1) ^ 1] + AIDX(ri0));
        float4 e0 = evr[0], e1 = evr[1];
        v2f S0 = (v2f){e0.x, e0.x} * tw[0][0];
        v2f S1 = (v2f){e0.x, e0.x} * tw[0][1];
#define ROWFMA(EV, R)                                                          \
        { S0 += (v2f){EV, EV} * tw[R][0];                                      \
          S1 += (v2f){EV, EV} * tw[R][1]; }
        ROWFMA(e0.y, 1) ROWFMA(e0.z, 2) ROWFMA(e0.w, 3)
        ROWFMA(e1.x, 4) ROWFMA(e1.y, 5) ROWFMA(e1.z, 6) ROWFMA(e1.w, 7)
#undef ROWFMA
        // cross-lane sum over 16 row-groups: xor1, xor2, xor4, xor8 (DPP)
        {
          v2f o0, o1;
          o0.x = dpp_f<0xB1>(S0.x); o0.y = dpp_f<0xB1>(S0.y);
          o1.x = dpp_f<0xB1>(S1.x); o1.y = dpp_f<0xB1>(S1.y);
          S0 += o0; S1 += o1;
          o0.x = dpp_f<0x4E>(S0.x); o0.y = dpp_f<0x4E>(S0.y);
          o1.x = dpp_f<0x4E>(S1.x); o1.y = dpp_f<0x4E>(S1.y);
          S0 += o0; S1 += o1;
          o0.x = dpp_f<0x141>(S0.x); o0.y = dpp_f<0x141>(S0.y);
          o1.x = dpp_f<0x141>(S1.x); o1.y = dpp_f<0x141>(S1.y);
          S0 += o0; S1 += o1;
          o0.x = dpp_f<0x140>(S0.x); o0.y = dpp_f<0x140>(S0.y);
          o1.x = dpp_f<0x140>(S1.x); o1.y = dpp_f<0x140>(S1.y);
          S0 += o0; S1 += o1;
        }
        float4 em2 = emC[s];
        float evn0 = S0.x * __expf(em2.x);
        float evn1 = S0.y * __expf(em2.y);
        float evn2 = S1.x * __expf(em2.z);
        float evn3 = S1.y * __expf(em2.w);
        if (s == 0) { evn0 *= r; evn1 *= r; evn2 *= r; evn3 *= r; }
        if (rrg == 0)
          *(float4*)(ev[t & 1] + AIDX(rj0)) =
              make_float4(evn0, evn1, evn2, evn3);
        if (s == 3) {
          float wm = fmaxf(fmaxf(evn0, evn1), fmaxf(evn2, evn3));  // 16-uniform
          wm = fmaxf(wm, swz16_f(wm));        // xor16 -> 32-uniform
          if ((tid & 31) == 0) wmax[tid >> 5] = wm;
        }
        BARRIER_LGKM();
      }
#pragma unroll
      for (int s = 0; s < 4; ++s) emC[s] = emN[s];
    }

    const float* evf = ev[(L - 1) & 1];
    {
      float ssum = (tid < KK) ? evf[AIDX(tid)] : 0.0f;
#pragma unroll
      for (int mm = 1; mm < 64; mm <<= 1) ssum += __shfl_xor(ssum, mm);
      if ((tid & 63) == 0) rs[tid >> 6] = ssum;
    }
    float sc = 0.0f;
    for (int tt2 = tid; tt2 < L; tt2 += 512) {
      int lab = labels[b * TT + tt2];
      sc += logits[(b * TT + tt2) * KK + lab];
      if (tt2 >= 1) sc += trans[labels[b * TT + tt2 - 1] * KK + lab];
    }
#pragma unroll
    for (int mm = 1; mm < 64; mm <<= 1) sc += __shfl_xor(sc, mm);
    if ((tid & 63) == 0) rsc[tid >> 6] = sc;
    __syncthreads();
    if (tid == 0) {
      float es = rs[0]; float scf = rsc[0];
#pragma unroll
      for (int w = 1; w < 8; ++w) { es += rs[w]; scf += rsc[w]; }
      negll[b] = (Cln + logf(es)) - scf;
    }
  }
}

__global__ void crf_loss_reduce(const float* __restrict__ negll, float* __restrict__ out) {
  int tid = threadIdx.x;
  float v = negll[tid];
#pragma unroll
  for (int m = 1; m < 64; m <<= 1) v += __shfl_xor(v, m);
  __shared__ float p[4];
  if ((tid & 63) == 0) p[tid >> 6] = v;
  __syncthreads();
  if (tid == 0) out[0] = p[0] + p[1] + p[2] + p[3];
}

extern "C" void kernel_launch(void* const* d_in, const int* in_sizes, int n_in,
                              void* d_out, int out_size, void* d_ws, size_t ws_size,
                              hipStream_t stream) {
  const float* logits   = (const float*)d_in[0];
  const int*   labels   = (const int*)d_in[1];
  const int*   seq_lens = (const int*)d_in[2];
  const float* trans    = (const float*)d_in[3];
  float* out = (float*)d_out;

  float* negll = (float*)d_ws;                          // [0, 1KB): 256 floats
  const size_t M_OFF = 4096;
  const size_t NEED = M_OFF + (size_t)BB * TT * KK * 4;   // ~67.1 MB

  float* mOut = (float*)((char*)d_ws + M_OFF);          // [4KB, 4KB+67.1MB)
  (void)NEED;
  crf_main<<<2 * BB, 512, 0, stream>>>(logits, labels, seq_lens, trans,
                                       out + 1, negll, mOut);
  crf_loss_reduce<<<1, 256, 0, stream>>>(negll, out);
}